// Round 1
// baseline (5196.198 us; speedup 1.0000x reference)
//
#include <hip/hip_runtime.h>
#include <hip/hip_bf16.h>
#include <stdint.h>

// SpatialTransformer: encoder GEMM+LN -> 29-step recurrent transformer stack
// (persistent cooperative kernel, 8 WGs, bf16 MFMA, 1 global barrier/layer)
// -> decoder GEMM (write-bound, fragment-packed bf16 MFMA).
//
// R1 change (fence-free coherent barrier):
//   The old gbar used agent-scope ACQUIRE spins + __threadfence, each of which
//   lowers to buffer_inv sc1 / buffer_wbl2 sc1 on gfx950 -- invalidating the
//   XCD's entire L2 every poll iteration, forcing ~768KB/WG/layer of read-only
//   weight frags to refetch from L3 every layer (~35us/layer of the 42us).
//   Now: K/V exchange uses RELAXED+AGENT atomics (sc1 write-through stores,
//   sc1 coherent loads -- coherent at L3 with NO cache maintenance), and the
//   barrier itself is relaxed. Zero buffer_inv in the whole scan; weights stay
//   L2-hot across all 116 layers. Ordering payload->flag comes from the
//   s_waitcnt vmcnt(0) the compiler emits at __syncthreads before the arrive.
//
// All MFMA operands are pre-packed into per-lane fragment order:
//   A-frag: lane holds A[row=lane&15][k=(lane>>4)*8+j], j=0..7
//   B-frag: lane holds B[k=(lane>>4)*8+j][col=lane&15]
//   C/D   : col=lane&15, row=(lane>>4)*4+reg   (m89-verified)
// Since we pack both sides ourselves with one convention, any internal k-order
// permutation cancels.

#define IMGSZ 16384
#define NWG 8
#define LTOT 116   // 29 steps * 4 layers

typedef __attribute__((ext_vector_type(8))) short bf16x8;
typedef __attribute__((ext_vector_type(4))) float f32x4;

__device__ __forceinline__ unsigned short f2bf(float f){
  unsigned int u = __builtin_bit_cast(unsigned int, f);
  unsigned int r = (u + 0x7fffu + ((u >> 16) & 1u)) >> 16;   // RNE
  return (unsigned short)r;
}

__device__ __forceinline__ f32x4 mfma16(bf16x8 a, bf16x8 b, f32x4 c){
  return __builtin_amdgcn_mfma_f32_16x16x32_bf16(a, b, c, 0, 0, 0);
}

__device__ __forceinline__ float rsum16(float x){
  x += __shfl_xor(x, 1, 64); x += __shfl_xor(x, 2, 64);
  x += __shfl_xor(x, 4, 64); x += __shfl_xor(x, 8, 64);
  return x;
}
__device__ __forceinline__ float rmax16(float x){
  x = fmaxf(x, __shfl_xor(x, 1, 64)); x = fmaxf(x, __shfl_xor(x, 2, 64));
  x = fmaxf(x, __shfl_xor(x, 4, 64)); x = fmaxf(x, __shfl_xor(x, 8, 64));
  return x;
}

// agent-coherent (sc1) K/V accessors -- no cache-maintenance instructions.
__device__ __forceinline__ void st_kv(unsigned short* p, unsigned short v){
  __hip_atomic_store(p, v, __ATOMIC_RELAXED, __HIP_MEMORY_SCOPE_AGENT);
}
__device__ __forceinline__ bf16x8 ld_kv16(const unsigned short* p){
  typedef __attribute__((ext_vector_type(2))) unsigned long long u64x2;
  unsigned long long lo = __hip_atomic_load((const unsigned long long*)p,
                                            __ATOMIC_RELAXED, __HIP_MEMORY_SCOPE_AGENT);
  unsigned long long hi = __hip_atomic_load((const unsigned long long*)p + 1,
                                            __ATOMIC_RELAXED, __HIP_MEMORY_SCOPE_AGENT);
  u64x2 v; v[0] = lo; v[1] = hi;
  return __builtin_bit_cast(bf16x8, v);
}

// A-fragment LDS index for a 16x256 bf16 operand stored as [kt(8)][lane(64)][j(8)]
__device__ __forceinline__ int afidx(int row, int c){
  return ((c >> 5) << 9) + ((row + (((c >> 3) & 3) << 4)) << 3) + (c & 7);
}

// ---------------- weight pre-pack (once per launch) ----------------
// encWf: 16 nt * 512 kt frags ; decWf: 1024 nt * 8 kt ; scanWf: 4 layers *
// [qkv 48nt*8kt | Wo 16*8 | W1 16*8 | W2 16*8] = 768 frags/layer
__global__ void pack_weights(const float* __restrict__ encW, const float* __restrict__ decW,
                             const float* __restrict__ Wqkv, const float* __restrict__ Wo,
                             const float* __restrict__ W1, const float* __restrict__ W2,
                             unsigned short* __restrict__ encWf, unsigned short* __restrict__ decWf,
                             unsigned short* __restrict__ scanWf)
{
  int wid = blockIdx.x * 4 + (threadIdx.x >> 6);
  int lane = threadIdx.x & 63;
  int g = lane >> 4, c0 = lane & 15;
  const float* W; int ncols, k0, n0; unsigned short* dst;
  if (wid < 8192){
    int nt = wid >> 9, kt = wid & 511;
    W = encW; ncols = 256; k0 = kt * 32; n0 = nt * 16;
    dst = encWf + ((size_t)wid << 9);
  } else if (wid < 16384){
    int f = wid - 8192;
    int nt = f >> 3, kt = f & 7;
    W = decW; ncols = IMGSZ; k0 = kt * 32; n0 = nt * 16;
    dst = decWf + ((size_t)f << 9);
  } else if (wid < 19456){
    int f = wid - 16384;
    int layer = f / 768;
    int r = f - layer * 768;
    if (r < 384){
      int nt = r >> 3, kt = r & 7;
      W = Wqkv + (size_t)layer * 256 * 768; ncols = 768; k0 = kt * 32; n0 = nt * 16;
    } else if (r < 512){
      int rr = r - 384; int nt = rr >> 3, kt = rr & 7;
      W = Wo + (size_t)layer * 65536; ncols = 256; k0 = kt * 32; n0 = nt * 16;
    } else if (r < 640){
      int rr = r - 512; int nt = rr >> 3, kt = rr & 7;
      W = W1 + (size_t)layer * 65536; ncols = 256; k0 = kt * 32; n0 = nt * 16;
    } else {
      int rr = r - 640; int nt = rr >> 3, kt = rr & 7;
      W = W2 + (size_t)layer * 65536; ncols = 256; k0 = kt * 32; n0 = nt * 16;
    }
    dst = scanWf + ((size_t)f << 9);
  } else return;
  unsigned int p[4];
  #pragma unroll
  for (int jj = 0; jj < 4; jj++){
    unsigned short lo = f2bf(W[(size_t)(k0 + g * 8 + 2 * jj    ) * ncols + n0 + c0]);
    unsigned short hi = f2bf(W[(size_t)(k0 + g * 8 + 2 * jj + 1) * ncols + n0 + c0]);
    p[jj] = (unsigned int)lo | ((unsigned int)hi << 16);
  }
  *(uint4*)(dst + lane * 8) = make_uint4(p[0], p[1], p[2], p[3]);
}

// ---------------- encoder: x0 @ enc_W, split-K into 32 partials ----------------
// grid = mb(2) * nb(4) * kc(32) = 256 blocks; block: M64 x N64 x K512
__global__ void enc_gemm(const float* __restrict__ x, const unsigned short* __restrict__ encWf,
                         float* __restrict__ part)
{
  int bid = blockIdx.x;
  int kc = bid & 31, nb = (bid >> 5) & 3, mb = bid >> 7;
  int tid = threadIdx.x, lane = tid & 63, w = tid >> 6;
  int g = lane >> 4, c0 = lane & 15;
  int mt = mb * 4 + w;
  const float* xrow = x + (size_t)(mt * 16 + c0) * (30 * IMGSZ);  // frame 0 of batch row
  f32x4 zero = {0.f, 0.f, 0.f, 0.f};
  f32x4 acc[4] = {zero, zero, zero, zero};
  for (int kk = 0; kk < 16; kk++){
    int ktg = (kc << 4) + kk;
    const float* xp = xrow + ktg * 32 + g * 8;
    float4 xa = *(const float4*)xp;
    float4 xb = *(const float4*)(xp + 4);
    bf16x8 a;
    a[0] = (short)f2bf(xa.x); a[1] = (short)f2bf(xa.y);
    a[2] = (short)f2bf(xa.z); a[3] = (short)f2bf(xa.w);
    a[4] = (short)f2bf(xb.x); a[5] = (short)f2bf(xb.y);
    a[6] = (short)f2bf(xb.z); a[7] = (short)f2bf(xb.w);
    #pragma unroll
    for (int i = 0; i < 4; i++){
      bf16x8 b = *(const bf16x8*)(encWf + (((size_t)(nb * 4 + i) * 512 + ktg) << 9) + lane * 8);
      acc[i] = mfma16(a, b, acc[i]);
    }
  }
  #pragma unroll
  for (int i = 0; i < 4; i++)
    #pragma unroll
    for (int reg = 0; reg < 4; reg++)
      part[((size_t)(kc << 7) + mt * 16 + g * 4 + reg) * 256 + (nb * 4 + i) * 16 + c0] = acc[i][reg];
}

// ---------------- encoder LN: reduce 32 partials + bias + LN -> s0, preds[0] ----------------
__global__ void enc_ln(const float* __restrict__ part, const float* __restrict__ enc_b,
                       const float* __restrict__ gg, const float* __restrict__ bb,
                       float* __restrict__ s0, unsigned short* __restrict__ predsf)
{
  int mt = blockIdx.x;
  int tid = threadIdx.x;
  int row = tid >> 4, cc = tid & 15;
  float v[16]; float sum = 0.f;
  #pragma unroll
  for (int k = 0; k < 16; k++){
    int c = cc + (k << 4);
    float a = enc_b[c];
    for (int kcb = 0; kcb < 32; kcb++)
      a += part[((size_t)(kcb << 7) + mt * 16 + row) * 256 + c];
    v[k] = a; sum += a;
  }
  sum = rsum16(sum);
  float mu = sum * (1.f / 256.f);
  float s2 = 0.f;
  #pragma unroll
  for (int k = 0; k < 16; k++){ float d = v[k] - mu; s2 += d * d; }
  s2 = rsum16(s2);
  float rs = rsqrtf(s2 * (1.f / 256.f) + 1e-5f);
  #pragma unroll
  for (int k = 0; k < 16; k++){
    int c = cc + (k << 4);
    float o = (v[k] - mu) * rs * gg[c] + bb[c];
    s0[(size_t)(mt * 16 + row) * 256 + c] = o;
    predsf[((size_t)(mt * 8 + (c >> 5)) << 9) + ((row + (((c >> 3) & 3) << 4)) << 3) + (c & 7)] = f2bf(o);
  }
}

// ---------------- cross-WG barrier (8 co-resident WGs) ----------------
// RELAXED atomics only: no buffer_inv / buffer_wbl2 anywhere. The K/V payload
// is itself agent-coherent (sc1 write-through stores + sc1 loads), so no cache
// maintenance is required for visibility. Payload-before-flag ordering comes
// from the s_waitcnt vmcnt(0) emitted at the __syncthreads below (all sc1
// stores acked at the coherence point before thread 0 issues the flag store).
// bar[0] = arrive counter; bar[32] = release flag (separate 128B line).
__device__ __forceinline__ void gbar(unsigned int* bar, int epoch){
  __syncthreads();          // drains vmcnt(0): all K/V sc1 stores are at L3
  if (threadIdx.x == 0){
    unsigned int target = (unsigned int)(epoch + 1) * NWG;
    unsigned int t = __hip_atomic_fetch_add(&bar[0], 1u, __ATOMIC_RELAXED, __HIP_MEMORY_SCOPE_AGENT);
    if (t == target - 1u){
      __hip_atomic_store(&bar[32], target, __ATOMIC_RELAXED, __HIP_MEMORY_SCOPE_AGENT);
    } else {
      while (__hip_atomic_load(&bar[32], __ATOMIC_RELAXED, __HIP_MEMORY_SCOPE_AGENT) < target){ }
    }
  }
  __syncthreads();
}

// ---------------- persistent scan: 29 steps x 4 layers ----------------
// WG wg owns batch rows wg*16..wg*16+15. wave w == head w in attention.
__launch_bounds__(256, 1)
__global__ void scan_kernel(const float* __restrict__ s0, const unsigned short* __restrict__ scanWf,
    const float* __restrict__ bqkv, const float* __restrict__ bo_g,
    const float* __restrict__ b1_g, const float* __restrict__ b2_g,
    const float* __restrict__ ln1g, const float* __restrict__ ln1b,
    const float* __restrict__ ln2g, const float* __restrict__ ln2b,
    const float* __restrict__ dng, const float* __restrict__ dnb,
    unsigned short* __restrict__ kvf, unsigned short* __restrict__ predsf,
    unsigned int* bar)
{
  __shared__ float res[16][264];    // current residual base / state (fp32)
  __shared__ float xscr[16][264];   // matmul output scratch needing row-ops
  __shared__ unsigned short A0[4096];      // A-frag ping
  __shared__ unsigned short A1[4096];      // A-frag pong
  __shared__ unsigned short qf[4][1024];   // per-wave q A-frags (16x64)
  __shared__ unsigned short pf[4][2048];   // per-wave softmax(P) A-frags (16x128)
  int tid = threadIdx.x, lane = tid & 63, w = tid >> 6;
  int g = lane >> 4, c0 = lane & 15;
  int wg = blockIdx.x, r0 = wg * 16;

  { // prologue: state <- s0
    int row = tid >> 4, cc = tid & 15;
    #pragma unroll
    for (int k = 0; k < 16; k++){
      int c = cc + (k << 4);
      float vv = s0[(size_t)(r0 + row) * 256 + c];
      res[row][c] = vv;
      A0[afidx(row, c)] = f2bf(vv);
    }
  }
  __syncthreads();

  int ntl[12];
  #pragma unroll
  for (int i = 0; i < 4; i++){ ntl[i] = 4 * w + i; ntl[4 + i] = 16 + 4 * w + i; ntl[8 + i] = 32 + 4 * w + i; }

  for (int l = 0; l < LTOT; l++){
    int lw = l & 3;
    const unsigned short* Wq  = scanWf + ((size_t)(lw * 768) << 9);
    const unsigned short* WoF = Wq + (384u << 9);
    const unsigned short* W1F = Wq + (512u << 9);
    const unsigned short* W2F = Wq + (640u << 9);
    unsigned short* kb = kvf + (size_t)(l & 1) * 65536;   // parity-double-buffered K/V

    // ---- qkv = h @ Wqkv + bqkv ; q -> qf (x0.125), k/v -> global frag buffers ----
    {
      f32x4 zero = {0, 0, 0, 0};
      f32x4 acc[12];
      #pragma unroll
      for (int i = 0; i < 12; i++) acc[i] = zero;
      for (int kt = 0; kt < 8; kt++){
        bf16x8 a = *(const bf16x8*)&A0[(kt << 9) + lane * 8];
        #pragma unroll
        for (int i = 0; i < 12; i++){
          bf16x8 b = *(const bf16x8*)(Wq + (((size_t)(ntl[i] << 3) + kt) << 9) + lane * 8);
          acc[i] = mfma16(a, b, acc[i]);
        }
      }
      #pragma unroll
      for (int i = 0; i < 12; i++){
        int ntg = ntl[i];
        int cg = (ntg << 4) + c0;
        float bias = bqkv[lw * 768 + cg];
        #pragma unroll
        for (int reg = 0; reg < 4; reg++){
          float vv = acc[i][reg] + bias;
          int row = g * 4 + reg;
          int f = cg & 63;
          if (ntg < 16){
            qf[w][((f >> 5) << 9) + ((row + (((f >> 3) & 3) << 4)) << 3) + (f & 7)] = f2bf(vv * 0.125f);
          } else if (ntg < 32){
            int key = r0 + row;   // B-frag for q@k^T: B[feat][key]
            st_kv(&kb[(((w * 2 + (f >> 5)) << 3) + (key >> 4)) * 512 + ((((f >> 3) & 3) << 4) + (key & 15)) * 8 + (f & 7)], f2bf(vv));
          } else {
            int key = r0 + row;   // B-frag for a@v: B[key][feat]
            st_kv(&kb[32768 + (((w * 4 + (key >> 5)) << 2) + (f >> 4)) * 512 + ((((key >> 3) & 3) << 4) + (f & 15)) * 8 + (key & 7)], f2bf(vv));
          }
        }
      }
    }
    gbar(bar, l);

    // ---- scores = q @ k^T ; online row softmax (in-wave, 16-lane shuffles) ----
    {
      f32x4 zero = {0, 0, 0, 0};
      f32x4 sc[8];
      #pragma unroll
      for (int i = 0; i < 8; i++) sc[i] = zero;
      #pragma unroll
      for (int kt = 0; kt < 2; kt++){
        bf16x8 a = *(const bf16x8*)&qf[w][(kt << 9) + lane * 8];
        #pragma unroll
        for (int nt = 0; nt < 8; nt++){
          bf16x8 b = ld_kv16(kb + (((w * 2 + kt) << 3) + nt) * 512 + lane * 8);
          sc[nt] = mfma16(a, b, sc[nt]);
        }
      }
      #pragma unroll
      for (int reg = 0; reg < 4; reg++){
        float m = sc[0][reg];
        #pragma unroll
        for (int nt = 1; nt < 8; nt++) m = fmaxf(m, sc[nt][reg]);
        m = rmax16(m);
        float p[8]; float s = 0.f;
        #pragma unroll
        for (int nt = 0; nt < 8; nt++){ p[nt] = __expf(sc[nt][reg] - m); s += p[nt]; }
        s = rsum16(s);
        float inv = 1.f / s;
        int row = g * 4 + reg;
        #pragma unroll
        for (int nt = 0; nt < 8; nt++){
          int key = (nt << 4) + c0;
          pf[w][((key >> 5) << 9) + ((row + (((key >> 3) & 3) << 4)) << 3) + (key & 7)] = f2bf(p[nt] * inv);
        }
      }
    }
    __syncthreads();

    // ---- o = a @ v (head cols 64w..64w+63) -> pack into A1 ----
    {
      f32x4 zero = {0, 0, 0, 0};
      f32x4 oacc[4];
      #pragma unroll
      for (int i = 0; i < 4; i++) oacc[i] = zero;
      #pragma unroll
      for (int kt = 0; kt < 4; kt++){
        bf16x8 a = *(const bf16x8*)&pf[w][(kt << 9) + lane * 8];
        #pragma unroll
        for (int nt = 0; nt < 4; nt++){
          bf16x8 b = ld_kv16(kb + 32768 + (((w * 4 + kt) << 2) + nt) * 512 + lane * 8);
          oacc[nt] = mfma16(a, b, oacc[nt]);
        }
      }
      #pragma unroll
      for (int nt = 0; nt < 4; nt++)
        #pragma unroll
        for (int reg = 0; reg < 4; reg++){
          int c = (w << 6) + (nt << 4) + c0;
          A1[afidx(g * 4 + reg, c)] = f2bf(oacc[nt][reg]);
        }
    }
    __syncthreads();

    // ---- o @ Wo -> xscr ----
    {
      f32x4 zero = {0, 0, 0, 0};
      f32x4 acc[4];
      #pragma unroll
      for (int i = 0; i < 4; i++) acc[i] = zero;
      for (int kt = 0; kt < 8; kt++){
        bf16x8 a = *(const bf16x8*)&A1[(kt << 9) + lane * 8];
        #pragma unroll
        for (int i = 0; i < 4; i++){
          bf16x8 b = *(const bf16x8*)(WoF + (((size_t)((4 * w + i) << 3) + kt) << 9) + lane * 8);
          acc[i] = mfma16(a, b, acc[i]);
        }
      }
      #pragma unroll
      for (int i = 0; i < 4; i++)
        #pragma unroll
        for (int reg = 0; reg < 4; reg++)
          xscr[g * 4 + reg][(w << 6) + (i << 4) + c0] = acc[i][reg];
    }
    __syncthreads();

    // ---- LN1 over (xscr + bo + res) -> res (h1), pack A0 ----
    {
      int row = tid >> 4, cc = tid & 15;
      const float* bo_l = bo_g + lw * 256;
      const float* g1 = ln1g + lw * 256;
      const float* bn1 = ln1b + lw * 256;
      float v[16]; float sum = 0.f;
      #pragma unroll
      for (int k = 0; k < 16; k++){
        int c = cc + (k << 4);
        float t = xscr[row][c] + bo_l[c] + res[row][c];
        v[k] = t; sum += t;
      }
      sum = rsum16(sum);
      float mu = sum * (1.f / 256.f);
      float s2 = 0.f;
      #pragma unroll
      for (int k = 0; k < 16; k++){ float d = v[k] - mu; s2 += d * d; }
      s2 = rsum16(s2);
      float rs = rsqrtf(s2 * (1.f / 256.f) + 1e-5f);
      #pragma unroll
      for (int k = 0; k < 16; k++){
        int c = cc + (k << 4);
        float o = (v[k] - mu) * rs * g1[c] + bn1[c];
        res[row][c] = o;
        A0[afidx(row, c)] = f2bf(o);
      }
    }
    __syncthreads();

    // ---- ff1 = relu(h1 @ W1 + b1) -> A1 (no row-ops, pack directly) ----
    {
      f32x4 zero = {0, 0, 0, 0};
      f32x4 acc[4];
      #pragma unroll
      for (int i = 0; i < 4; i++) acc[i] = zero;
      for (int kt = 0; kt < 8; kt++){
        bf16x8 a = *(const bf16x8*)&A0[(kt << 9) + lane * 8];
        #pragma unroll
        for (int i = 0; i < 4; i++){
          bf16x8 b = *(const bf16x8*)(W1F + (((size_t)((4 * w + i) << 3) + kt) << 9) + lane * 8);
          acc[i] = mfma16(a, b, acc[i]);
        }
      }
      const float* b1l = b1_g + lw * 256;
      #pragma unroll
      for (int i = 0; i < 4; i++)
        #pragma unroll
        for (int reg = 0; reg < 4; reg++){
          int c = (w << 6) + (i << 4) + c0;
          float vv = fmaxf(acc[i][reg] + b1l[c], 0.f);
          A1[afidx(g * 4 + reg, c)] = f2bf(vv);
        }
    }
    __syncthreads();

    // ---- ff2 = ff1 @ W2 -> xscr ----
    {
      f32x4 zero = {0, 0, 0, 0};
      f32x4 acc[4];
      #pragma unroll
      for (int i = 0; i < 4; i++) acc[i] = zero;
      for (int kt = 0; kt < 8; kt++){
        bf16x8 a = *(const bf16x8*)&A1[(kt << 9) + lane * 8];
        #pragma unroll
        for (int i = 0; i < 4; i++){
          bf16x8 b = *(const bf16x8*)(W2F + (((size_t)((4 * w + i) << 3) + kt) << 9) + lane * 8);
          acc[i] = mfma16(a, b, acc[i]);
        }
      }
      #pragma unroll
      for (int i = 0; i < 4; i++)
        #pragma unroll
        for (int reg = 0; reg < 4; reg++)
          xscr[g * 4 + reg][(w << 6) + (i << 4) + c0] = acc[i][reg];
    }
    __syncthreads();

    // ---- LN2 (+ final decn LN + preds store at step end) -> res, A0 ----
    {
      int row = tid >> 4, cc = tid & 15;
      const float* b2l = b2_g + lw * 256;
      const float* g2 = ln2g + lw * 256;
      const float* bn2 = ln2b + lw * 256;
      float v[16]; float sum = 0.f;
      #pragma unroll
      for (int k = 0; k < 16; k++){
        int c = cc + (k << 4);
        float t = xscr[row][c] + b2l[c] + res[row][c];
        v[k] = t; sum += t;
      }
      sum = rsum16(sum);
      float mu = sum * (1.f / 256.f);
      float s2 = 0.f;
      #pragma unroll
      for (int k = 0; k < 16; k++){ float d = v[k] - mu; s2 += d * d; }
      s2 = rsum16(s2);
      float rs = rsqrtf(s2 * (1.f / 256.f) + 1e-5f);
      #pragma unroll
      for (int k = 0; k < 16; k++){
        int c = cc + (k << 4);
        v[k] = (v[k] - mu) * rs * g2[c] + bn2[c];
      }
      if (lw == 3){
        float sum2 = 0.f;
        #pragma unroll
        for (int k = 0; k < 16; k++) sum2 += v[k];
        sum2 = rsum16(sum2);
        float mu2 = sum2 * (1.f / 256.f);
        float s22 = 0.f;
        #pragma unroll
        for (int k = 0; k < 16; k++){ float d = v[k] - mu2; s22 += d * d; }
        s22 = rsum16(s22);
        float rs2 = rsqrtf(s22 * (1.f / 256.f) + 1e-5f);
        int t_out = (l >> 2) + 1;
        size_t mbase = (size_t)(t_out * 8 + wg) * 8;
        #pragma unroll
        for (int k = 0; k < 16; k++){
          int c = cc + (k << 4);
          float o2 = (v[k] - mu2) * rs2 * dng[c] + dnb[c];
          res[row][c] = o2;
          unsigned short bv = f2bf(o2);
          A0[afidx(row, c)] = bv;
          predsf[((mbase + (c >> 5)) << 9) + ((row + (((c >> 3) & 3) << 4)) << 3) + (c & 7)] = bv;
        }
      } else {
        #pragma unroll
        for (int k = 0; k < 16; k++){
          int c = cc + (k << 4);
          res[row][c] = v[k];
          A0[afidx(row, c)] = f2bf(v[k]);
        }
      }
    }
    __syncthreads();
  }
}

// ---------------- decoder: out[b,t,:] = preds[t,b,:] @ dec_W + dec_b ----------------
// grid = mb(30) * nb(256); block tile: M128 (8 mtiles) x N64, K=256.
__global__ void dec_gemm(const unsigned short* __restrict__ predsf, const unsigned short* __restrict__ decWf,
                         const float* __restrict__ dec_b, float* __restrict__ out)
{
  __shared__ float cs[128][68];
  int bid = blockIdx.x;
  int nb = bid & 255, mb = bid >> 8;
  int tid = threadIdx.x, lane = tid & 63, w = tid >> 6;
  int g = lane >> 4, c0 = lane & 15;
  f32x4 zero = {0.f, 0.f, 0.f, 0.f};
  f32x4 acc[2][4] = {{zero, zero, zero, zero}, {zero, zero, zero, zero}};
  #pragma unroll
  for (int kt = 0; kt < 8; kt++){
    bf16x8 a0 = *(const bf16x8*)(predsf + (((size_t)(mb * 8 + 2 * w    ) * 8 + kt) << 9) + lane * 8);
    bf16x8 a1 = *(const bf16x8*)(predsf + (((size_t)(mb * 8 + 2 * w + 1) * 8 + kt) << 9) + lane * 8);
    #pragma unroll
    for (int i = 0; i < 4; i++){
      bf16x8 b = *(const bf16x8*)(decWf + (((size_t)(nb * 4 + i) * 8 + kt) << 9) + lane * 8);
      acc[0][i] = mfma16(a0, b, acc[0][i]);
      acc[1][i] = mfma16(a1, b, acc[1][i]);
    }
  }
  #pragma unroll
  for (int mi = 0; mi < 2; mi++)
    #pragma unroll
    for (int i = 0; i < 4; i++)
      #pragma unroll
      for (int reg = 0; reg < 4; reg++)
        cs[(2 * w + mi) * 16 + g * 4 + reg][i * 16 + c0] = acc[mi][i][reg];
  __syncthreads();
  int row = tid >> 1, seg = tid & 1;   // row == batch index b; t == mb
  #pragma unroll
  for (int q = 0; q < 8; q++){
    int c = seg * 32 + q * 4;
    float4 vv = *(float4*)&cs[row][c];
    float4 db = *(const float4*)(dec_b + nb * 64 + c);
    vv.x += db.x; vv.y += db.y; vv.z += db.z; vv.w += db.w;
    *(float4*)(out + ((size_t)row * 30 + mb) * IMGSZ + nb * 64 + c) = vv;
  }
}

extern "C" void kernel_launch(void* const* d_in, const int* in_sizes, int n_in,
                              void* d_out, int out_size, void* d_ws, size_t ws_size,
                              hipStream_t stream)
{
  (void)in_sizes; (void)n_in; (void)out_size; (void)ws_size;
  const float* x      = (const float*)d_in[0];
  const float* enc_W  = (const float*)d_in[1];
  const float* enc_b  = (const float*)d_in[2];
  const float* encn_g = (const float*)d_in[3];
  const float* encn_b = (const float*)d_in[4];
  const float* dec_W  = (const float*)d_in[5];
  const float* dec_b  = (const float*)d_in[6];
  const float* decn_g = (const float*)d_in[7];
  const float* decn_b = (const float*)d_in[8];
  const float* Wqkv   = (const float*)d_in[9];
  const float* bqkv   = (const float*)d_in[10];
  const float* Wo     = (const float*)d_in[11];
  const float* bo     = (const float*)d_in[12];
  const float* W1     = (const float*)d_in[13];
  const float* b1     = (const float*)d_in[14];
  const float* W2     = (const float*)d_in[15];
  const float* b2     = (const float*)d_in[16];
  const float* ln1_g  = (const float*)d_in[17];
  const float* ln1_b  = (const float*)d_in[18];
  const float* ln2_g  = (const float*)d_in[19];
  const float* ln2_b  = (const float*)d_in[20];

  char* ws = (char*)d_ws;
  // ws layout (all offsets 512B-aligned), total ~26.5 MB
  unsigned int* bar      = (unsigned int*)(ws);              // 512 B
  float* s0              = (float*)(ws + 512);               // 128*256*4      = 131072
  float* part            = (float*)(ws + 131584);            // 32*128*256*4   = 4194304
  unsigned short* encWf  = (unsigned short*)(ws + 4325888);  // 8192*1024      = 8388608
  unsigned short* decWf  = (unsigned short*)(ws + 12714496); // 8192*1024      = 8388608
  unsigned short* scanWf = (unsigned short*)(ws + 21103104); // 3072*1024      = 3145728
  unsigned short* predsf = (unsigned short*)(ws + 24248832); // 240*8*1024     = 1966080
  unsigned short* kvf    = (unsigned short*)(ws + 26214912); // 2*128*1024     = 262144

  hipMemsetAsync(bar, 0, 512, stream);
  pack_weights<<<4864, 256, 0, stream>>>(enc_W, dec_W, Wqkv, Wo, W1, W2, encWf, decWf, scanWf);
  enc_gemm<<<256, 256, 0, stream>>>(x, encWf, part);
  enc_ln<<<8, 256, 0, stream>>>(part, enc_b, encn_g, encn_b, s0, predsf);
  scan_kernel<<<NWG, 256, 0, stream>>>(s0, scanWf, bqkv, bo, b1, b2,
                                       ln1_g, ln1_b, ln2_g, ln2_b,
                                       decn_g, decn_b, kvf, predsf, bar);
  dec_gemm<<<30 * 256, 256, 0, stream>>>(predsf, decWf, dec_b, (float*)d_out);
}

// Round 2
// 2749.658 us; speedup vs baseline: 1.8898x; 1.8898x over previous
//
#include <hip/hip_runtime.h>
#include <hip/hip_bf16.h>
#include <stdint.h>

// SpatialTransformer: encoder GEMM+LN -> 29-step recurrent transformer stack
// (persistent cooperative kernel, 8 WGs, bf16 MFMA, 1 global barrier/layer)
// -> decoder GEMM (write-bound, fragment-packed bf16 MFMA).
//
// R2 change (16-wave scan WGs for latency hiding):
//   R1 counters: MfmaUtil 0.115%, VALUBusy 0.205%, Occupancy 0.389% -- active
//   CUs stalled ~90%: 1 wave/SIMD meant every weight/KV load latency was fully
//   exposed. Now scan_kernel runs 1024 threads (16 waves, 4/SIMD): all phases
//   re-partitioned across 16 waves (qkv 3 nt/wave, scores via LDS f32 scratch,
//   softmax 4 rows/wave, Wo/W1/W2 1 nt/wave, LN 1 row/wave). 4x TLP + 4x fewer
//   loads per wave.
//
// All MFMA operands are pre-packed into per-lane fragment order:
//   A-frag: lane holds A[row=lane&15][k=(lane>>4)*8+j], j=0..7
//   B-frag: lane holds B[k=(lane>>4)*8+j][col=lane&15]
//   C/D   : col=lane&15, row=(lane>>4)*4+reg   (m89-verified)
// Since we pack both sides ourselves with one convention, any internal k-order
// permutation cancels.

#define IMGSZ 16384
#define NWG 8
#define LTOT 116   // 29 steps * 4 layers

typedef __attribute__((ext_vector_type(8))) short bf16x8;
typedef __attribute__((ext_vector_type(4))) float f32x4;

__device__ __forceinline__ unsigned short f2bf(float f){
  unsigned int u = __builtin_bit_cast(unsigned int, f);
  unsigned int r = (u + 0x7fffu + ((u >> 16) & 1u)) >> 16;   // RNE
  return (unsigned short)r;
}

__device__ __forceinline__ f32x4 mfma16(bf16x8 a, bf16x8 b, f32x4 c){
  return __builtin_amdgcn_mfma_f32_16x16x32_bf16(a, b, c, 0, 0, 0);
}

__device__ __forceinline__ float rsum16(float x){
  x += __shfl_xor(x, 1, 64); x += __shfl_xor(x, 2, 64);
  x += __shfl_xor(x, 4, 64); x += __shfl_xor(x, 8, 64);
  return x;
}
__device__ __forceinline__ float rmax16(float x){
  x = fmaxf(x, __shfl_xor(x, 1, 64)); x = fmaxf(x, __shfl_xor(x, 2, 64));
  x = fmaxf(x, __shfl_xor(x, 4, 64)); x = fmaxf(x, __shfl_xor(x, 8, 64));
  return x;
}
__device__ __forceinline__ float rsum64(float x){
  x += __shfl_xor(x, 1, 64); x += __shfl_xor(x, 2, 64);
  x += __shfl_xor(x, 4, 64); x += __shfl_xor(x, 8, 64);
  x += __shfl_xor(x, 16, 64); x += __shfl_xor(x, 32, 64);
  return x;
}

// agent-coherent (sc1) K/V accessors -- no cache-maintenance instructions.
__device__ __forceinline__ void st_kv(unsigned short* p, unsigned short v){
  __hip_atomic_store(p, v, __ATOMIC_RELAXED, __HIP_MEMORY_SCOPE_AGENT);
}
__device__ __forceinline__ bf16x8 ld_kv16(const unsigned short* p){
  typedef __attribute__((ext_vector_type(2))) unsigned long long u64x2;
  unsigned long long lo = __hip_atomic_load((const unsigned long long*)p,
                                            __ATOMIC_RELAXED, __HIP_MEMORY_SCOPE_AGENT);
  unsigned long long hi = __hip_atomic_load((const unsigned long long*)p + 1,
                                            __ATOMIC_RELAXED, __HIP_MEMORY_SCOPE_AGENT);
  u64x2 v; v[0] = lo; v[1] = hi;
  return __builtin_bit_cast(bf16x8, v);
}

// A-fragment LDS index for a 16x256 bf16 operand stored as [kt(8)][lane(64)][j(8)]
__device__ __forceinline__ int afidx(int row, int c){
  return ((c >> 5) << 9) + ((row + (((c >> 3) & 3) << 4)) << 3) + (c & 7);
}

// ---------------- weight pre-pack (once per launch) ----------------
// encWf: 16 nt * 512 kt frags ; decWf: 1024 nt * 8 kt ; scanWf: 4 layers *
// [qkv 48nt*8kt | Wo 16*8 | W1 16*8 | W2 16*8] = 768 frags/layer
__global__ void pack_weights(const float* __restrict__ encW, const float* __restrict__ decW,
                             const float* __restrict__ Wqkv, const float* __restrict__ Wo,
                             const float* __restrict__ W1, const float* __restrict__ W2,
                             unsigned short* __restrict__ encWf, unsigned short* __restrict__ decWf,
                             unsigned short* __restrict__ scanWf)
{
  int wid = blockIdx.x * 4 + (threadIdx.x >> 6);
  int lane = threadIdx.x & 63;
  int g = lane >> 4, c0 = lane & 15;
  const float* W; int ncols, k0, n0; unsigned short* dst;
  if (wid < 8192){
    int nt = wid >> 9, kt = wid & 511;
    W = encW; ncols = 256; k0 = kt * 32; n0 = nt * 16;
    dst = encWf + ((size_t)wid << 9);
  } else if (wid < 16384){
    int f = wid - 8192;
    int nt = f >> 3, kt = f & 7;
    W = decW; ncols = IMGSZ; k0 = kt * 32; n0 = nt * 16;
    dst = decWf + ((size_t)f << 9);
  } else if (wid < 19456){
    int f = wid - 16384;
    int layer = f / 768;
    int r = f - layer * 768;
    if (r < 384){
      int nt = r >> 3, kt = r & 7;
      W = Wqkv + (size_t)layer * 256 * 768; ncols = 768; k0 = kt * 32; n0 = nt * 16;
    } else if (r < 512){
      int rr = r - 384; int nt = rr >> 3, kt = rr & 7;
      W = Wo + (size_t)layer * 65536; ncols = 256; k0 = kt * 32; n0 = nt * 16;
    } else if (r < 640){
      int rr = r - 512; int nt = rr >> 3, kt = rr & 7;
      W = W1 + (size_t)layer * 65536; ncols = 256; k0 = kt * 32; n0 = nt * 16;
    } else {
      int rr = r - 640; int nt = rr >> 3, kt = rr & 7;
      W = W2 + (size_t)layer * 65536; ncols = 256; k0 = kt * 32; n0 = nt * 16;
    }
    dst = scanWf + ((size_t)f << 9);
  } else return;
  unsigned int p[4];
  #pragma unroll
  for (int jj = 0; jj < 4; jj++){
    unsigned short lo = f2bf(W[(size_t)(k0 + g * 8 + 2 * jj    ) * ncols + n0 + c0]);
    unsigned short hi = f2bf(W[(size_t)(k0 + g * 8 + 2 * jj + 1) * ncols + n0 + c0]);
    p[jj] = (unsigned int)lo | ((unsigned int)hi << 16);
  }
  *(uint4*)(dst + lane * 8) = make_uint4(p[0], p[1], p[2], p[3]);
}

// ---------------- encoder: x0 @ enc_W, split-K into 32 partials ----------------
// grid = mb(2) * nb(4) * kc(32) = 256 blocks; block: M64 x N64 x K512
__global__ void enc_gemm(const float* __restrict__ x, const unsigned short* __restrict__ encWf,
                         float* __restrict__ part)
{
  int bid = blockIdx.x;
  int kc = bid & 31, nb = (bid >> 5) & 3, mb = bid >> 7;
  int tid = threadIdx.x, lane = tid & 63, w = tid >> 6;
  int g = lane >> 4, c0 = lane & 15;
  int mt = mb * 4 + w;
  const float* xrow = x + (size_t)(mt * 16 + c0) * (30 * IMGSZ);  // frame 0 of batch row
  f32x4 zero = {0.f, 0.f, 0.f, 0.f};
  f32x4 acc[4] = {zero, zero, zero, zero};
  for (int kk = 0; kk < 16; kk++){
    int ktg = (kc << 4) + kk;
    const float* xp = xrow + ktg * 32 + g * 8;
    float4 xa = *(const float4*)xp;
    float4 xb = *(const float4*)(xp + 4);
    bf16x8 a;
    a[0] = (short)f2bf(xa.x); a[1] = (short)f2bf(xa.y);
    a[2] = (short)f2bf(xa.z); a[3] = (short)f2bf(xa.w);
    a[4] = (short)f2bf(xb.x); a[5] = (short)f2bf(xb.y);
    a[6] = (short)f2bf(xb.z); a[7] = (short)f2bf(xb.w);
    #pragma unroll
    for (int i = 0; i < 4; i++){
      bf16x8 b = *(const bf16x8*)(encWf + (((size_t)(nb * 4 + i) * 512 + ktg) << 9) + lane * 8);
      acc[i] = mfma16(a, b, acc[i]);
    }
  }
  #pragma unroll
  for (int i = 0; i < 4; i++)
    #pragma unroll
    for (int reg = 0; reg < 4; reg++)
      part[((size_t)(kc << 7) + mt * 16 + g * 4 + reg) * 256 + (nb * 4 + i) * 16 + c0] = acc[i][reg];
}

// ---------------- encoder LN: reduce 32 partials + bias + LN -> s0, preds[0] ----------------
__global__ void enc_ln(const float* __restrict__ part, const float* __restrict__ enc_b,
                       const float* __restrict__ gg, const float* __restrict__ bb,
                       float* __restrict__ s0, unsigned short* __restrict__ predsf)
{
  int mt = blockIdx.x;
  int tid = threadIdx.x;
  int row = tid >> 4, cc = tid & 15;
  float v[16]; float sum = 0.f;
  #pragma unroll
  for (int k = 0; k < 16; k++){
    int c = cc + (k << 4);
    float a = enc_b[c];
    for (int kcb = 0; kcb < 32; kcb++)
      a += part[((size_t)(kcb << 7) + mt * 16 + row) * 256 + c];
    v[k] = a; sum += a;
  }
  sum = rsum16(sum);
  float mu = sum * (1.f / 256.f);
  float s2 = 0.f;
  #pragma unroll
  for (int k = 0; k < 16; k++){ float d = v[k] - mu; s2 += d * d; }
  s2 = rsum16(s2);
  float rs = rsqrtf(s2 * (1.f / 256.f) + 1e-5f);
  #pragma unroll
  for (int k = 0; k < 16; k++){
    int c = cc + (k << 4);
    float o = (v[k] - mu) * rs * gg[c] + bb[c];
    s0[(size_t)(mt * 16 + row) * 256 + c] = o;
    predsf[((size_t)(mt * 8 + (c >> 5)) << 9) + ((row + (((c >> 3) & 3) << 4)) << 3) + (c & 7)] = f2bf(o);
  }
}

// ---------------- cross-WG barrier (8 co-resident WGs) ----------------
// RELAXED atomics only: no buffer_inv / buffer_wbl2 anywhere. The K/V payload
// is itself agent-coherent (sc1 write-through stores + sc1 loads), so no cache
// maintenance is required for visibility. Payload-before-flag ordering comes
// from the s_waitcnt vmcnt(0) emitted at the __syncthreads below.
// bar[0] = arrive counter; bar[32] = release flag (separate 128B line).
__device__ __forceinline__ void gbar(unsigned int* bar, int epoch){
  __syncthreads();          // drains vmcnt(0): all K/V sc1 stores are at L3
  if (threadIdx.x == 0){
    unsigned int target = (unsigned int)(epoch + 1) * NWG;
    unsigned int t = __hip_atomic_fetch_add(&bar[0], 1u, __ATOMIC_RELAXED, __HIP_MEMORY_SCOPE_AGENT);
    if (t == target - 1u){
      __hip_atomic_store(&bar[32], target, __ATOMIC_RELAXED, __HIP_MEMORY_SCOPE_AGENT);
    } else {
      while (__hip_atomic_load(&bar[32], __ATOMIC_RELAXED, __HIP_MEMORY_SCOPE_AGENT) < target){ }
    }
  }
  __syncthreads();
}

// ---------------- persistent scan: 29 steps x 4 layers ----------------
// WG wg owns batch rows wg*16..wg*16+15. 16 waves (4/SIMD) per WG.
__launch_bounds__(1024, 1)
__global__ void scan_kernel(const float* __restrict__ s0, const unsigned short* __restrict__ scanWf,
    const float* __restrict__ bqkv, const float* __restrict__ bo_g,
    const float* __restrict__ b1_g, const float* __restrict__ b2_g,
    const float* __restrict__ ln1g, const float* __restrict__ ln1b,
    const float* __restrict__ ln2g, const float* __restrict__ ln2b,
    const float* __restrict__ dng, const float* __restrict__ dnb,
    unsigned short* __restrict__ kvf, unsigned short* __restrict__ predsf,
    unsigned int* bar)
{
  __shared__ float res[16][264];    // current residual base / state (fp32)
  __shared__ float xscr[16][264];   // matmul output scratch needing row-ops
  __shared__ float scr[4][16][132]; // raw attention scores f32 (head, qrow, key)
  __shared__ __align__(16) unsigned short A0[4096];      // A-frag ping
  __shared__ __align__(16) unsigned short A1[4096];      // A-frag pong
  __shared__ __align__(16) unsigned short qf[4][1024];   // per-head q A-frags (16x64)
  __shared__ __align__(16) unsigned short pf[4][2048];   // per-head softmax(P) A-frags (16x128)
  int tid = threadIdx.x, lane = tid & 63, w = tid >> 6;
  int g = lane >> 4, c0 = lane & 15;
  int wg = blockIdx.x, r0 = wg * 16;

  { // prologue: state <- s0 (16 waves: row w, 4 cols/lane)
    int row = w, cc = lane;
    #pragma unroll
    for (int k = 0; k < 4; k++){
      int c = cc + (k << 6);
      float vv = s0[(size_t)(r0 + row) * 256 + c];
      res[row][c] = vv;
      A0[afidx(row, c)] = f2bf(vv);
    }
  }
  __syncthreads();

  for (int l = 0; l < LTOT; l++){
    int lw = l & 3;
    const unsigned short* Wq  = scanWf + ((size_t)(lw * 768) << 9);
    const unsigned short* WoF = Wq + (384u << 9);
    const unsigned short* W1F = Wq + (512u << 9);
    const unsigned short* W2F = Wq + (640u << 9);
    unsigned short* kb = kvf + (size_t)(l & 1) * 65536;   // parity-double-buffered K/V

    // ---- qkv = h @ Wqkv + bqkv ; 3 nt-tiles per wave (48 total) ----
    // q -> qf (x0.125), k/v -> global frag buffers (head index from ntg).
    {
      f32x4 zero = {0, 0, 0, 0};
      f32x4 acc[3] = {zero, zero, zero};
      for (int kt = 0; kt < 8; kt++){
        bf16x8 a = *(const bf16x8*)&A0[(kt << 9) + lane * 8];
        #pragma unroll
        for (int i = 0; i < 3; i++){
          bf16x8 b = *(const bf16x8*)(Wq + (((size_t)((3 * w + i) << 3) + kt) << 9) + lane * 8);
          acc[i] = mfma16(a, b, acc[i]);
        }
      }
      #pragma unroll
      for (int i = 0; i < 3; i++){
        int ntg = 3 * w + i;
        int cg = (ntg << 4) + c0;
        float bias = bqkv[lw * 768 + cg];
        int f = ((ntg & 3) << 4) | c0;
        #pragma unroll
        for (int reg = 0; reg < 4; reg++){
          float vv = acc[i][reg] + bias;
          int row = g * 4 + reg;
          if (ntg < 16){
            int hh = ntg >> 2;
            qf[hh][((f >> 5) << 9) + ((row + (((f >> 3) & 3) << 4)) << 3) + (f & 7)] = f2bf(vv * 0.125f);
          } else if (ntg < 32){
            int hh = (ntg - 16) >> 2;
            int key = r0 + row;   // B-frag for q@k^T: B[feat][key]
            st_kv(&kb[(((hh * 2 + (f >> 5)) << 3) + (key >> 4)) * 512 + ((((f >> 3) & 3) << 4) + (key & 15)) * 8 + (f & 7)], f2bf(vv));
          } else {
            int hh = (ntg - 32) >> 2;
            int key = r0 + row;   // B-frag for a@v: B[key][feat]
            st_kv(&kb[32768 + (((hh * 4 + (key >> 5)) << 2) + (f >> 4)) * 512 + ((((key >> 3) & 3) << 4) + (f & 15)) * 8 + (key & 7)], f2bf(vv));
          }
        }
      }
    }
    gbar(bar, l);

    // ---- scores = q @ k^T : 16 waves = 4 heads x 4 key-tile-pairs -> scr (f32) ----
    {
      int hh = w >> 2, np = w & 3;
      f32x4 zero = {0, 0, 0, 0};
      f32x4 sc[2] = {zero, zero};
      #pragma unroll
      for (int kt = 0; kt < 2; kt++){
        bf16x8 a = *(const bf16x8*)&qf[hh][(kt << 9) + lane * 8];
        #pragma unroll
        for (int j = 0; j < 2; j++){
          int nt = 2 * np + j;
          bf16x8 b = ld_kv16(kb + (((hh * 2 + kt) << 3) + nt) * 512 + lane * 8);
          sc[j] = mfma16(a, b, sc[j]);
        }
      }
      #pragma unroll
      for (int j = 0; j < 2; j++)
        #pragma unroll
        for (int reg = 0; reg < 4; reg++)
          scr[hh][g * 4 + reg][(2 * np + j) * 16 + c0] = sc[j][reg];
    }
    __syncthreads();

    // ---- softmax: 16 waves = 4 heads x 4 row-quads; 8 keys/lane -> pf (bf16 frags) ----
    {
      int hh = w & 3, rq = w >> 2;
      int rloc = lane >> 4, kc = lane & 15;
      int row = rq * 4 + rloc;
      float4 vlo = *(const float4*)&scr[hh][row][kc * 8];
      float4 vhi = *(const float4*)&scr[hh][row][kc * 8 + 4];
      float p[8] = {vlo.x, vlo.y, vlo.z, vlo.w, vhi.x, vhi.y, vhi.z, vhi.w};
      float m = p[0];
      #pragma unroll
      for (int j = 1; j < 8; j++) m = fmaxf(m, p[j]);
      m = rmax16(m);
      float s = 0.f;
      #pragma unroll
      for (int j = 0; j < 8; j++){ p[j] = __expf(p[j] - m); s += p[j]; }
      s = rsum16(s);
      float inv = 1.f / s;
      unsigned int u[4];
      #pragma unroll
      for (int t = 0; t < 4; t++){
        unsigned short lo = f2bf(p[2 * t] * inv);
        unsigned short hi = f2bf(p[2 * t + 1] * inv);
        u[t] = (unsigned int)lo | ((unsigned int)hi << 16);
      }
      int base = ((kc >> 2) << 9) + ((row + ((kc & 3) << 4)) << 3);
      *(uint4*)&pf[hh][base] = make_uint4(u[0], u[1], u[2], u[3]);
    }
    __syncthreads();

    // ---- o = a @ v : 16 waves = 4 heads x 4 out-tiles -> pack into A1 ----
    {
      int hh = w >> 2, nt = w & 3;
      f32x4 zero = {0, 0, 0, 0};
      f32x4 oacc = zero;
      #pragma unroll
      for (int kt = 0; kt < 4; kt++){
        bf16x8 a = *(const bf16x8*)&pf[hh][(kt << 9) + lane * 8];
        bf16x8 b = ld_kv16(kb + 32768 + (((hh * 4 + kt) << 2) + nt) * 512 + lane * 8);
        oacc = mfma16(a, b, oacc);
      }
      #pragma unroll
      for (int reg = 0; reg < 4; reg++){
        int c = (hh << 6) + (nt << 4) + c0;
        A1[afidx(g * 4 + reg, c)] = f2bf(oacc[reg]);
      }
    }
    __syncthreads();

    // ---- o @ Wo -> xscr (1 nt/wave) ----
    {
      f32x4 zero = {0, 0, 0, 0};
      f32x4 acc = zero;
      for (int kt = 0; kt < 8; kt++){
        bf16x8 a = *(const bf16x8*)&A1[(kt << 9) + lane * 8];
        bf16x8 b = *(const bf16x8*)(WoF + (((size_t)(w << 3) + kt) << 9) + lane * 8);
        acc = mfma16(a, b, acc);
      }
      #pragma unroll
      for (int reg = 0; reg < 4; reg++)
        xscr[g * 4 + reg][(w << 4) + c0] = acc[reg];
    }
    __syncthreads();

    // ---- LN1 over (xscr + bo + res) -> res (h1), pack A0 (1 row/wave) ----
    {
      int row = w, cc = lane;
      const float* bo_l = bo_g + lw * 256;
      const float* g1 = ln1g + lw * 256;
      const float* bn1 = ln1b + lw * 256;
      float v[4]; float sum = 0.f;
      #pragma unroll
      for (int k = 0; k < 4; k++){
        int c = cc + (k << 6);
        float t = xscr[row][c] + bo_l[c] + res[row][c];
        v[k] = t; sum += t;
      }
      sum = rsum64(sum);
      float mu = sum * (1.f / 256.f);
      float s2 = 0.f;
      #pragma unroll
      for (int k = 0; k < 4; k++){ float d = v[k] - mu; s2 += d * d; }
      s2 = rsum64(s2);
      float rs = rsqrtf(s2 * (1.f / 256.f) + 1e-5f);
      #pragma unroll
      for (int k = 0; k < 4; k++){
        int c = cc + (k << 6);
        float o = (v[k] - mu) * rs * g1[c] + bn1[c];
        res[row][c] = o;
        A0[afidx(row, c)] = f2bf(o);
      }
    }
    __syncthreads();

    // ---- ff1 = relu(h1 @ W1 + b1) -> A1 (1 nt/wave, pack directly) ----
    {
      f32x4 zero = {0, 0, 0, 0};
      f32x4 acc = zero;
      for (int kt = 0; kt < 8; kt++){
        bf16x8 a = *(const bf16x8*)&A0[(kt << 9) + lane * 8];
        bf16x8 b = *(const bf16x8*)(W1F + (((size_t)(w << 3) + kt) << 9) + lane * 8);
        acc = mfma16(a, b, acc);
      }
      const float* b1l = b1_g + lw * 256;
      #pragma unroll
      for (int reg = 0; reg < 4; reg++){
        int c = (w << 4) + c0;
        float vv = fmaxf(acc[reg] + b1l[c], 0.f);
        A1[afidx(g * 4 + reg, c)] = f2bf(vv);
      }
    }
    __syncthreads();

    // ---- ff2 = ff1 @ W2 -> xscr (1 nt/wave) ----
    {
      f32x4 zero = {0, 0, 0, 0};
      f32x4 acc = zero;
      for (int kt = 0; kt < 8; kt++){
        bf16x8 a = *(const bf16x8*)&A1[(kt << 9) + lane * 8];
        bf16x8 b = *(const bf16x8*)(W2F + (((size_t)(w << 3) + kt) << 9) + lane * 8);
        acc = mfma16(a, b, acc);
      }
      #pragma unroll
      for (int reg = 0; reg < 4; reg++)
        xscr[g * 4 + reg][(w << 4) + c0] = acc[reg];
    }
    __syncthreads();

    // ---- LN2 (+ final decn LN + preds store at step end) -> res, A0 (1 row/wave) ----
    {
      int row = w, cc = lane;
      const float* b2l = b2_g + lw * 256;
      const float* g2 = ln2g + lw * 256;
      const float* bn2 = ln2b + lw * 256;
      float v[4]; float sum = 0.f;
      #pragma unroll
      for (int k = 0; k < 4; k++){
        int c = cc + (k << 6);
        float t = xscr[row][c] + b2l[c] + res[row][c];
        v[k] = t; sum += t;
      }
      sum = rsum64(sum);
      float mu = sum * (1.f / 256.f);
      float s2 = 0.f;
      #pragma unroll
      for (int k = 0; k < 4; k++){ float d = v[k] - mu; s2 += d * d; }
      s2 = rsum64(s2);
      float rs = rsqrtf(s2 * (1.f / 256.f) + 1e-5f);
      #pragma unroll
      for (int k = 0; k < 4; k++){
        int c = cc + (k << 6);
        v[k] = (v[k] - mu) * rs * g2[c] + bn2[c];
      }
      if (lw == 3){
        float sum2 = 0.f;
        #pragma unroll
        for (int k = 0; k < 4; k++) sum2 += v[k];
        sum2 = rsum64(sum2);
        float mu2 = sum2 * (1.f / 256.f);
        float s22 = 0.f;
        #pragma unroll
        for (int k = 0; k < 4; k++){ float d = v[k] - mu2; s22 += d * d; }
        s22 = rsum64(s22);
        float rs2 = rsqrtf(s22 * (1.f / 256.f) + 1e-5f);
        int t_out = (l >> 2) + 1;
        size_t mbase = (size_t)(t_out * 8 + wg) * 8;
        #pragma unroll
        for (int k = 0; k < 4; k++){
          int c = cc + (k << 6);
          float o2 = (v[k] - mu2) * rs2 * dng[c] + dnb[c];
          res[row][c] = o2;
          unsigned short bv = f2bf(o2);
          A0[afidx(row, c)] = bv;
          predsf[((mbase + (c >> 5)) << 9) + ((row + (((c >> 3) & 3) << 4)) << 3) + (c & 7)] = bv;
        }
      } else {
        #pragma unroll
        for (int k = 0; k < 4; k++){
          int c = cc + (k << 6);
          res[row][c] = v[k];
          A0[afidx(row, c)] = f2bf(v[k]);
        }
      }
    }
    __syncthreads();
  }
}

// ---------------- decoder: out[b,t,:] = preds[t,b,:] @ dec_W + dec_b ----------------
// grid = mb(30) * nb(256); block tile: M128 (8 mtiles) x N64, K=256.
__global__ void dec_gemm(const unsigned short* __restrict__ predsf, const unsigned short* __restrict__ decWf,
                         const float* __restrict__ dec_b, float* __restrict__ out)
{
  __shared__ float cs[128][68];
  int bid = blockIdx.x;
  int nb = bid & 255, mb = bid >> 8;
  int tid = threadIdx.x, lane = tid & 63, w = tid >> 6;
  int g = lane >> 4, c0 = lane & 15;
  f32x4 zero = {0.f, 0.f, 0.f, 0.f};
  f32x4 acc[2][4] = {{zero, zero, zero, zero}, {zero, zero, zero, zero}};
  #pragma unroll
  for (int kt = 0; kt < 8; kt++){
    bf16x8 a0 = *(const bf16x8*)(predsf + (((size_t)(mb * 8 + 2 * w    ) * 8 + kt) << 9) + lane * 8);
    bf16x8 a1 = *(const bf16x8*)(predsf + (((size_t)(mb * 8 + 2 * w + 1) * 8 + kt) << 9) + lane * 8);
    #pragma unroll
    for (int i = 0; i < 4; i++){
      bf16x8 b = *(const bf16x8*)(decWf + (((size_t)(nb * 4 + i) * 8 + kt) << 9) + lane * 8);
      acc[0][i] = mfma16(a0, b, acc[0][i]);
      acc[1][i] = mfma16(a1, b, acc[1][i]);
    }
  }
  #pragma unroll
  for (int mi = 0; mi < 2; mi++)
    #pragma unroll
    for (int i = 0; i < 4; i++)
      #pragma unroll
      for (int reg = 0; reg < 4; reg++)
        cs[(2 * w + mi) * 16 + g * 4 + reg][i * 16 + c0] = acc[mi][i][reg];
  __syncthreads();
  int row = tid >> 1, seg = tid & 1;   // row == batch index b; t == mb
  #pragma unroll
  for (int q = 0; q < 8; q++){
    int c = seg * 32 + q * 4;
    float4 vv = *(float4*)&cs[row][c];
    float4 db = *(const float4*)(dec_b + nb * 64 + c);
    vv.x += db.x; vv.y += db.y; vv.z += db.z; vv.w += db.w;
    *(float4*)(out + ((size_t)row * 30 + mb) * IMGSZ + nb * 64 + c) = vv;
  }
}

extern "C" void kernel_launch(void* const* d_in, const int* in_sizes, int n_in,
                              void* d_out, int out_size, void* d_ws, size_t ws_size,
                              hipStream_t stream)
{
  (void)in_sizes; (void)n_in; (void)out_size; (void)ws_size;
  const float* x      = (const float*)d_in[0];
  const float* enc_W  = (const float*)d_in[1];
  const float* enc_b  = (const float*)d_in[2];
  const float* encn_g = (const float*)d_in[3];
  const float* encn_b = (const float*)d_in[4];
  const float* dec_W  = (const float*)d_in[5];
  const float* dec_b  = (const float*)d_in[6];
  const float* decn_g = (const float*)d_in[7];
  const float* decn_b = (const float*)d_in[8];
  const float* Wqkv   = (const float*)d_in[9];
  const float* bqkv   = (const float*)d_in[10];
  const float* Wo     = (const float*)d_in[11];
  const float* bo     = (const float*)d_in[12];
  const float* W1     = (const float*)d_in[13];
  const float* b1     = (const float*)d_in[14];
  const float* W2     = (const float*)d_in[15];
  const float* b2     = (const float*)d_in[16];
  const float* ln1_g  = (const float*)d_in[17];
  const float* ln1_b  = (const float*)d_in[18];
  const float* ln2_g  = (const float*)d_in[19];
  const float* ln2_b  = (const float*)d_in[20];

  char* ws = (char*)d_ws;
  // ws layout (all offsets 512B-aligned), total ~26.5 MB
  unsigned int* bar      = (unsigned int*)(ws);              // 512 B
  float* s0              = (float*)(ws + 512);               // 128*256*4      = 131072
  float* part            = (float*)(ws + 131584);            // 32*128*256*4   = 4194304
  unsigned short* encWf  = (unsigned short*)(ws + 4325888);  // 8192*1024      = 8388608
  unsigned short* decWf  = (unsigned short*)(ws + 12714496); // 8192*1024      = 8388608
  unsigned short* scanWf = (unsigned short*)(ws + 21103104); // 3072*1024      = 3145728
  unsigned short* predsf = (unsigned short*)(ws + 24248832); // 240*8*1024     = 1966080
  unsigned short* kvf    = (unsigned short*)(ws + 26214912); // 2*128*1024     = 262144

  hipMemsetAsync(bar, 0, 512, stream);
  pack_weights<<<4864, 256, 0, stream>>>(enc_W, dec_W, Wqkv, Wo, W1, W2, encWf, decWf, scanWf);
  enc_gemm<<<256, 256, 0, stream>>>(x, encWf, part);
  enc_ln<<<8, 256, 0, stream>>>(part, enc_b, encn_g, encn_b, s0, predsf);
  scan_kernel<<<NWG, 1024, 0, stream>>>(s0, scanWf, bqkv, bo, b1, b2,
                                        ln1_g, ln1_b, ln2_g, ln2_b,
                                        decn_g, decn_b, kvf, predsf, bar);
  dec_gemm<<<30 * 256, 256, 0, stream>>>(predsf, decWf, dec_b, (float*)d_out);
}

// Round 3
// 2366.442 us; speedup vs baseline: 2.1958x; 1.1619x over previous
//
#include <hip/hip_runtime.h>
#include <hip/hip_bf16.h>
#include <stdint.h>

// SpatialTransformer: encoder GEMM+LN -> 29-step recurrent transformer stack
// (persistent cooperative kernel, 8 WGs, bf16 MFMA, 1 global barrier/layer)
// -> decoder GEMM (write-bound, fragment-packed bf16 MFMA).
//
// R3 change (coalesced K/V exchange):
//   R2 counters: FETCH 72MB / WRITE 48MB per dispatch vs 26MB working set --
//   the K/V exchange (128KB/layer payload) was written as 32 scattered 2B sc1
//   stores per thread; partial-line write-through forced TCC read-modify-write
//   (~4x fetch+write amplification) and the pre-gbar vmcnt(0) drain waited on
//   256K scattered L3 stores per layer. Now each WG stages its 16KB K/V
//   contribution in LDS (aliased over scr, which is only live post-gbar) in
//   final fragment layout, then copies to global as 2x8B agent-scope stores
//   per thread (full-line, 16B-aligned). Payload unchanged, amplification and
//   store-drain eliminated.
//
// All MFMA operands are pre-packed into per-lane fragment order:
//   A-frag: lane holds A[row=lane&15][k=(lane>>4)*8+j], j=0..7
//   B-frag: lane holds B[k=(lane>>4)*8+j][col=lane&15]
//   C/D   : col=lane&15, row=(lane>>4)*4+reg   (m89-verified)

#define IMGSZ 16384
#define NWG 8
#define LTOT 116   // 29 steps * 4 layers

typedef __attribute__((ext_vector_type(8))) short bf16x8;
typedef __attribute__((ext_vector_type(4))) float f32x4;

__device__ __forceinline__ unsigned short f2bf(float f){
  unsigned int u = __builtin_bit_cast(unsigned int, f);
  unsigned int r = (u + 0x7fffu + ((u >> 16) & 1u)) >> 16;   // RNE
  return (unsigned short)r;
}

__device__ __forceinline__ f32x4 mfma16(bf16x8 a, bf16x8 b, f32x4 c){
  return __builtin_amdgcn_mfma_f32_16x16x32_bf16(a, b, c, 0, 0, 0);
}

__device__ __forceinline__ float rsum16(float x){
  x += __shfl_xor(x, 1, 64); x += __shfl_xor(x, 2, 64);
  x += __shfl_xor(x, 4, 64); x += __shfl_xor(x, 8, 64);
  return x;
}
__device__ __forceinline__ float rmax16(float x){
  x = fmaxf(x, __shfl_xor(x, 1, 64)); x = fmaxf(x, __shfl_xor(x, 2, 64));
  x = fmaxf(x, __shfl_xor(x, 4, 64)); x = fmaxf(x, __shfl_xor(x, 8, 64));
  return x;
}
__device__ __forceinline__ float rsum64(float x){
  x += __shfl_xor(x, 1, 64); x += __shfl_xor(x, 2, 64);
  x += __shfl_xor(x, 4, 64); x += __shfl_xor(x, 8, 64);
  x += __shfl_xor(x, 16, 64); x += __shfl_xor(x, 32, 64);
  return x;
}

// agent-coherent (sc1) K/V accessors -- no cache-maintenance instructions.
__device__ __forceinline__ void st_kv64(unsigned long long* p, unsigned long long v){
  __hip_atomic_store(p, v, __ATOMIC_RELAXED, __HIP_MEMORY_SCOPE_AGENT);
}
__device__ __forceinline__ bf16x8 ld_kv16(const unsigned short* p){
  typedef __attribute__((ext_vector_type(2))) unsigned long long u64x2;
  unsigned long long lo = __hip_atomic_load((const unsigned long long*)p,
                                            __ATOMIC_RELAXED, __HIP_MEMORY_SCOPE_AGENT);
  unsigned long long hi = __hip_atomic_load((const unsigned long long*)p + 1,
                                            __ATOMIC_RELAXED, __HIP_MEMORY_SCOPE_AGENT);
  u64x2 v; v[0] = lo; v[1] = hi;
  return __builtin_bit_cast(bf16x8, v);
}

// A-fragment LDS index for a 16x256 bf16 operand stored as [kt(8)][lane(64)][j(8)]
__device__ __forceinline__ int afidx(int row, int c){
  return ((c >> 5) << 9) + ((row + (((c >> 3) & 3) << 4)) << 3) + (c & 7);
}

// ---------------- weight pre-pack (once per launch) ----------------
__global__ void pack_weights(const float* __restrict__ encW, const float* __restrict__ decW,
                             const float* __restrict__ Wqkv, const float* __restrict__ Wo,
                             const float* __restrict__ W1, const float* __restrict__ W2,
                             unsigned short* __restrict__ encWf, unsigned short* __restrict__ decWf,
                             unsigned short* __restrict__ scanWf)
{
  int wid = blockIdx.x * 4 + (threadIdx.x >> 6);
  int lane = threadIdx.x & 63;
  int g = lane >> 4, c0 = lane & 15;
  const float* W; int ncols, k0, n0; unsigned short* dst;
  if (wid < 8192){
    int nt = wid >> 9, kt = wid & 511;
    W = encW; ncols = 256; k0 = kt * 32; n0 = nt * 16;
    dst = encWf + ((size_t)wid << 9);
  } else if (wid < 16384){
    int f = wid - 8192;
    int nt = f >> 3, kt = f & 7;
    W = decW; ncols = IMGSZ; k0 = kt * 32; n0 = nt * 16;
    dst = decWf + ((size_t)f << 9);
  } else if (wid < 19456){
    int f = wid - 16384;
    int layer = f / 768;
    int r = f - layer * 768;
    if (r < 384){
      int nt = r >> 3, kt = r & 7;
      W = Wqkv + (size_t)layer * 256 * 768; ncols = 768; k0 = kt * 32; n0 = nt * 16;
    } else if (r < 512){
      int rr = r - 384; int nt = rr >> 3, kt = rr & 7;
      W = Wo + (size_t)layer * 65536; ncols = 256; k0 = kt * 32; n0 = nt * 16;
    } else if (r < 640){
      int rr = r - 512; int nt = rr >> 3, kt = rr & 7;
      W = W1 + (size_t)layer * 65536; ncols = 256; k0 = kt * 32; n0 = nt * 16;
    } else {
      int rr = r - 640; int nt = rr >> 3, kt = rr & 7;
      W = W2 + (size_t)layer * 65536; ncols = 256; k0 = kt * 32; n0 = nt * 16;
    }
    dst = scanWf + ((size_t)f << 9);
  } else return;
  unsigned int p[4];
  #pragma unroll
  for (int jj = 0; jj < 4; jj++){
    unsigned short lo = f2bf(W[(size_t)(k0 + g * 8 + 2 * jj    ) * ncols + n0 + c0]);
    unsigned short hi = f2bf(W[(size_t)(k0 + g * 8 + 2 * jj + 1) * ncols + n0 + c0]);
    p[jj] = (unsigned int)lo | ((unsigned int)hi << 16);
  }
  *(uint4*)(dst + lane * 8) = make_uint4(p[0], p[1], p[2], p[3]);
}

// ---------------- encoder: x0 @ enc_W, split-K into 32 partials ----------------
__global__ void enc_gemm(const float* __restrict__ x, const unsigned short* __restrict__ encWf,
                         float* __restrict__ part)
{
  int bid = blockIdx.x;
  int kc = bid & 31, nb = (bid >> 5) & 3, mb = bid >> 7;
  int tid = threadIdx.x, lane = tid & 63, w = tid >> 6;
  int g = lane >> 4, c0 = lane & 15;
  int mt = mb * 4 + w;
  const float* xrow = x + (size_t)(mt * 16 + c0) * (30 * IMGSZ);  // frame 0 of batch row
  f32x4 zero = {0.f, 0.f, 0.f, 0.f};
  f32x4 acc[4] = {zero, zero, zero, zero};
  for (int kk = 0; kk < 16; kk++){
    int ktg = (kc << 4) + kk;
    const float* xp = xrow + ktg * 32 + g * 8;
    float4 xa = *(const float4*)xp;
    float4 xb = *(const float4*)(xp + 4);
    bf16x8 a;
    a[0] = (short)f2bf(xa.x); a[1] = (short)f2bf(xa.y);
    a[2] = (short)f2bf(xa.z); a[3] = (short)f2bf(xa.w);
    a[4] = (short)f2bf(xb.x); a[5] = (short)f2bf(xb.y);
    a[6] = (short)f2bf(xb.z); a[7] = (short)f2bf(xb.w);
    #pragma unroll
    for (int i = 0; i < 4; i++){
      bf16x8 b = *(const bf16x8*)(encWf + (((size_t)(nb * 4 + i) * 512 + ktg) << 9) + lane * 8);
      acc[i] = mfma16(a, b, acc[i]);
    }
  }
  #pragma unroll
  for (int i = 0; i < 4; i++)
    #pragma unroll
    for (int reg = 0; reg < 4; reg++)
      part[((size_t)(kc << 7) + mt * 16 + g * 4 + reg) * 256 + (nb * 4 + i) * 16 + c0] = acc[i][reg];
}

// ---------------- encoder LN: reduce 32 partials + bias + LN -> s0, preds[0] ----------------
__global__ void enc_ln(const float* __restrict__ part, const float* __restrict__ enc_b,
                       const float* __restrict__ gg, const float* __restrict__ bb,
                       float* __restrict__ s0, unsigned short* __restrict__ predsf)
{
  int mt = blockIdx.x;
  int tid = threadIdx.x;
  int row = tid >> 4, cc = tid & 15;
  float v[16]; float sum = 0.f;
  #pragma unroll
  for (int k = 0; k < 16; k++){
    int c = cc + (k << 4);
    float a = enc_b[c];
    for (int kcb = 0; kcb < 32; kcb++)
      a += part[((size_t)(kcb << 7) + mt * 16 + row) * 256 + c];
    v[k] = a; sum += a;
  }
  sum = rsum16(sum);
  float mu = sum * (1.f / 256.f);
  float s2 = 0.f;
  #pragma unroll
  for (int k = 0; k < 16; k++){ float d = v[k] - mu; s2 += d * d; }
  s2 = rsum16(s2);
  float rs = rsqrtf(s2 * (1.f / 256.f) + 1e-5f);
  #pragma unroll
  for (int k = 0; k < 16; k++){
    int c = cc + (k << 4);
    float o = (v[k] - mu) * rs * gg[c] + bb[c];
    s0[(size_t)(mt * 16 + row) * 256 + c] = o;
    predsf[((size_t)(mt * 8 + (c >> 5)) << 9) + ((row + (((c >> 3) & 3) << 4)) << 3) + (c & 7)] = f2bf(o);
  }
}

// ---------------- cross-WG barrier (8 co-resident WGs) ----------------
// RELAXED atomics only: no buffer_inv / buffer_wbl2 anywhere. Payload (K/V) is
// agent-coherent sc1; payload->flag ordering via the vmcnt(0) drain at the
// __syncthreads below. bar[0]=arrive counter; bar[32]=release flag (own line).
__device__ __forceinline__ void gbar(unsigned int* bar, int epoch){
  __syncthreads();          // drains vmcnt(0): all K/V sc1 stores are at L3
  if (threadIdx.x == 0){
    unsigned int target = (unsigned int)(epoch + 1) * NWG;
    unsigned int t = __hip_atomic_fetch_add(&bar[0], 1u, __ATOMIC_RELAXED, __HIP_MEMORY_SCOPE_AGENT);
    if (t == target - 1u){
      __hip_atomic_store(&bar[32], target, __ATOMIC_RELAXED, __HIP_MEMORY_SCOPE_AGENT);
    } else {
      while (__hip_atomic_load(&bar[32], __ATOMIC_RELAXED, __HIP_MEMORY_SCOPE_AGENT) < target){ }
    }
  }
  __syncthreads();
}

// ---------------- persistent scan: 29 steps x 4 layers ----------------
// WG wg owns batch rows wg*16..wg*16+15. 16 waves (4/SIMD) per WG.
__launch_bounds__(1024, 1)
__global__ void scan_kernel(const float* __restrict__ s0, const unsigned short* __restrict__ scanWf,
    const float* __restrict__ bqkv, const float* __restrict__ bo_g,
    const float* __restrict__ b1_g, const float* __restrict__ b2_g,
    const float* __restrict__ ln1g, const float* __restrict__ ln1b,
    const float* __restrict__ ln2g, const float* __restrict__ ln2b,
    const float* __restrict__ dng, const float* __restrict__ dnb,
    unsigned short* __restrict__ kvf, unsigned short* __restrict__ predsf,
    unsigned int* bar)
{
  __shared__ float res[16][264];    // current residual base / state (fp32)
  __shared__ float xscr[16][264];   // matmul output scratch needing row-ops
  // scr: raw attention scores f32 (head, qrow, key). Only live AFTER gbar;
  // before gbar the same memory is the K/V staging buffer (16KB, frag layout).
  __shared__ __align__(16) float scr[4][16][132];
  __shared__ __align__(16) unsigned short A0[4096];      // A-frag ping
  __shared__ __align__(16) unsigned short A1[4096];      // A-frag pong
  __shared__ __align__(16) unsigned short qf[4][1024];   // per-head q A-frags (16x64)
  __shared__ __align__(16) unsigned short pf[4][2048];   // per-head softmax(P) A-frags (16x128)
  unsigned short* kvstage = (unsigned short*)&scr[0][0][0];  // [0,4096)=K, [4096,8192)=V (shorts)
  int tid = threadIdx.x, lane = tid & 63, w = tid >> 6;
  int g = lane >> 4, c0 = lane & 15;
  int wg = blockIdx.x, r0 = wg * 16;

  { // prologue: state <- s0 (16 waves: row w, 4 cols/lane)
    int row = w, cc = lane;
    #pragma unroll
    for (int k = 0; k < 4; k++){
      int c = cc + (k << 6);
      float vv = s0[(size_t)(r0 + row) * 256 + c];
      res[row][c] = vv;
      A0[afidx(row, c)] = f2bf(vv);
    }
  }
  __syncthreads();

  for (int l = 0; l < LTOT; l++){
    int lw = l & 3;
    const unsigned short* Wq  = scanWf + ((size_t)(lw * 768) << 9);
    const unsigned short* WoF = Wq + (384u << 9);
    const unsigned short* W1F = Wq + (512u << 9);
    const unsigned short* W2F = Wq + (640u << 9);
    unsigned short* kb = kvf + (size_t)(l & 1) * 65536;   // parity-double-buffered K/V

    // ---- qkv = h @ Wqkv + bqkv ; 3 nt-tiles per wave (48 total) ----
    // q -> qf (x0.125); k/v -> LDS staging (final fragment layout).
    {
      f32x4 zero = {0, 0, 0, 0};
      f32x4 acc[3] = {zero, zero, zero};
      for (int kt = 0; kt < 8; kt++){
        bf16x8 a = *(const bf16x8*)&A0[(kt << 9) + lane * 8];
        #pragma unroll
        for (int i = 0; i < 3; i++){
          bf16x8 b = *(const bf16x8*)(Wq + (((size_t)((3 * w + i) << 3) + kt) << 9) + lane * 8);
          acc[i] = mfma16(a, b, acc[i]);
        }
      }
      #pragma unroll
      for (int i = 0; i < 3; i++){
        int ntg = 3 * w + i;
        int cg = (ntg << 4) + c0;
        float bias = bqkv[lw * 768 + cg];
        int f = ((ntg & 3) << 4) | c0;
        #pragma unroll
        for (int reg = 0; reg < 4; reg++){
          float vv = acc[i][reg] + bias;
          int row = g * 4 + reg;
          if (ntg < 16){
            int hh = ntg >> 2;
            qf[hh][((f >> 5) << 9) + ((row + (((f >> 3) & 3) << 4)) << 3) + (f & 7)] = f2bf(vv * 0.125f);
          } else if (ntg < 32){
            int hh = (ntg - 16) >> 2;
            int kp = f >> 5;
            // local staging block (hh*2+kp), in-block offset over (f-group, row)
            kvstage[(hh * 2 + kp) * 512 + ((((f >> 3) & 3) << 4) + row) * 8 + (f & 7)] = f2bf(vv);
          } else {
            int hh = (ntg - 32) >> 2;
            int ft = (f >> 4) & 3;
            kvstage[4096 + (hh * 4 + ft) * 256 + (((row >> 3) & 1) << 7) + ((f & 15) << 3) + (row & 7)] = f2bf(vv);
          }
        }
      }
    }
    __syncthreads();   // staging complete

    // ---- cooperative coalesced K/V copy: LDS staging -> global (2x8B sc1/thread) ----
    {
      const unsigned long long* src = (const unsigned long long*)kvstage;
      unsigned long long d0 = src[tid * 2], d1 = src[tid * 2 + 1];
      size_t goff;   // u64 index into kb
      if (tid < 512){
        int bk = tid >> 6, inb = tid & 63;            // K: 8 blocks x 1KB
        goff = (size_t)(bk * 8 + wg) * 128 + inb * 2;
      } else {
        int tv = tid - 512;
        int bv = tv >> 5, inc = tv & 31;              // V: 16 chunks x 512B
        int hh = bv >> 2, ft = bv & 3;
        int bg = hh * 16 + (wg >> 1) * 4 + ft;
        goff = 8192 + (size_t)bg * 128 + ((size_t)(wg & 1) << 6) + inc * 2;
      }
      unsigned long long* dst = (unsigned long long*)kb + goff;
      st_kv64(dst, d0);
      st_kv64(dst + 1, d1);
    }
    gbar(bar, l);

    // ---- scores = q @ k^T : 16 waves = 4 heads x 4 key-tile-pairs -> scr (f32) ----
    {
      int hh = w >> 2, np = w & 3;
      f32x4 zero = {0, 0, 0, 0};
      f32x4 sc[2] = {zero, zero};
      #pragma unroll
      for (int kt = 0; kt < 2; kt++){
        bf16x8 a = *(const bf16x8*)&qf[hh][(kt << 9) + lane * 8];
        #pragma unroll
        for (int j = 0; j < 2; j++){
          int nt = 2 * np + j;
          bf16x8 b = ld_kv16(kb + (((hh * 2 + kt) << 3) + nt) * 512 + lane * 8);
          sc[j] = mfma16(a, b, sc[j]);
        }
      }
      #pragma unroll
      for (int j = 0; j < 2; j++)
        #pragma unroll
        for (int reg = 0; reg < 4; reg++)
          scr[hh][g * 4 + reg][(2 * np + j) * 16 + c0] = sc[j][reg];
    }
    __syncthreads();

    // ---- softmax: 16 waves = 4 heads x 4 row-quads; 8 keys/lane -> pf (bf16 frags) ----
    {
      int hh = w & 3, rq = w >> 2;
      int rloc = lane >> 4, kc = lane & 15;
      int row = rq * 4 + rloc;
      float4 vlo = *(const float4*)&scr[hh][row][kc * 8];
      float4 vhi = *(const float4*)&scr[hh][row][kc * 8 + 4];
      float p[8] = {vlo.x, vlo.y, vlo.z, vlo.w, vhi.x, vhi.y, vhi.z, vhi.w};
      float m = p[0];
      #pragma unroll
      for (int j = 1; j < 8; j++) m = fmaxf(m, p[j]);
      m = rmax16(m);
      float s = 0.f;
      #pragma unroll
      for (int j = 0; j < 8; j++){ p[j] = __expf(p[j] - m); s += p[j]; }
      s = rsum16(s);
      float inv = 1.f / s;
      unsigned int u[4];
      #pragma unroll
      for (int t = 0; t < 4; t++){
        unsigned short lo = f2bf(p[2 * t] * inv);
        unsigned short hi = f2bf(p[2 * t + 1] * inv);
        u[t] = (unsigned int)lo | ((unsigned int)hi << 16);
      }
      int base = ((kc >> 2) << 9) + ((row + ((kc & 3) << 4)) << 3);
      *(uint4*)&pf[hh][base] = make_uint4(u[0], u[1], u[2], u[3]);
    }
    __syncthreads();

    // ---- o = a @ v : 16 waves = 4 heads x 4 out-tiles -> pack into A1 ----
    {
      int hh = w >> 2, nt = w & 3;
      f32x4 zero = {0, 0, 0, 0};
      f32x4 oacc = zero;
      #pragma unroll
      for (int kt = 0; kt < 4; kt++){
        bf16x8 a = *(const bf16x8*)&pf[hh][(kt << 9) + lane * 8];
        bf16x8 b = ld_kv16(kb + 32768 + (((hh * 4 + kt) << 2) + nt) * 512 + lane * 8);
        oacc = mfma16(a, b, oacc);
      }
      #pragma unroll
      for (int reg = 0; reg < 4; reg++){
        int c = (hh << 6) + (nt << 4) + c0;
        A1[afidx(g * 4 + reg, c)] = f2bf(oacc[reg]);
      }
    }
    __syncthreads();

    // ---- o @ Wo -> xscr (1 nt/wave) ----
    {
      f32x4 zero = {0, 0, 0, 0};
      f32x4 acc = zero;
      for (int kt = 0; kt < 8; kt++){
        bf16x8 a = *(const bf16x8*)&A1[(kt << 9) + lane * 8];
        bf16x8 b = *(const bf16x8*)(WoF + (((size_t)(w << 3) + kt) << 9) + lane * 8);
        acc = mfma16(a, b, acc);
      }
      #pragma unroll
      for (int reg = 0; reg < 4; reg++)
        xscr[g * 4 + reg][(w << 4) + c0] = acc[reg];
    }
    __syncthreads();

    // ---- LN1 over (xscr + bo + res) -> res (h1), pack A0 (1 row/wave) ----
    {
      int row = w, cc = lane;
      const float* bo_l = bo_g + lw * 256;
      const float* g1 = ln1g + lw * 256;
      const float* bn1 = ln1b + lw * 256;
      float v[4]; float sum = 0.f;
      #pragma unroll
      for (int k = 0; k < 4; k++){
        int c = cc + (k << 6);
        float t = xscr[row][c] + bo_l[c] + res[row][c];
        v[k] = t; sum += t;
      }
      sum = rsum64(sum);
      float mu = sum * (1.f / 256.f);
      float s2 = 0.f;
      #pragma unroll
      for (int k = 0; k < 4; k++){ float d = v[k] - mu; s2 += d * d; }
      s2 = rsum64(s2);
      float rs = rsqrtf(s2 * (1.f / 256.f) + 1e-5f);
      #pragma unroll
      for (int k = 0; k < 4; k++){
        int c = cc + (k << 6);
        float o = (v[k] - mu) * rs * g1[c] + bn1[c];
        res[row][c] = o;
        A0[afidx(row, c)] = f2bf(o);
      }
    }
    __syncthreads();

    // ---- ff1 = relu(h1 @ W1 + b1) -> A1 (1 nt/wave, pack directly) ----
    {
      f32x4 zero = {0, 0, 0, 0};
      f32x4 acc = zero;
      for (int kt = 0; kt < 8; kt++){
        bf16x8 a = *(const bf16x8*)&A0[(kt << 9) + lane * 8];
        bf16x8 b = *(const bf16x8*)(W1F + (((size_t)(w << 3) + kt) << 9) + lane * 8);
        acc = mfma16(a, b, acc);
      }
      const float* b1l = b1_g + lw * 256;
      #pragma unroll
      for (int reg = 0; reg < 4; reg++){
        int c = (w << 4) + c0;
        float vv = fmaxf(acc[reg] + b1l[c], 0.f);
        A1[afidx(g * 4 + reg, c)] = f2bf(vv);
      }
    }
    __syncthreads();

    // ---- ff2 = ff1 @ W2 -> xscr (1 nt/wave) ----
    {
      f32x4 zero = {0, 0, 0, 0};
      f32x4 acc = zero;
      for (int kt = 0; kt < 8; kt++){
        bf16x8 a = *(const bf16x8*)&A1[(kt << 9) + lane * 8];
        bf16x8 b = *(const bf16x8*)(W2F + (((size_t)(w << 3) + kt) << 9) + lane * 8);
        acc = mfma16(a, b, acc);
      }
      #pragma unroll
      for (int reg = 0; reg < 4; reg++)
        xscr[g * 4 + reg][(w << 4) + c0] = acc[reg];
    }
    __syncthreads();

    // ---- LN2 (+ final decn LN + preds store at step end) -> res, A0 (1 row/wave) ----
    {
      int row = w, cc = lane;
      const float* b2l = b2_g + lw * 256;
      const float* g2 = ln2g + lw * 256;
      const float* bn2 = ln2b + lw * 256;
      float v[4]; float sum = 0.f;
      #pragma unroll
      for (int k = 0; k < 4; k++){
        int c = cc + (k << 6);
        float t = xscr[row][c] + b2l[c] + res[row][c];
        v[k] = t; sum += t;
      }
      sum = rsum64(sum);
      float mu = sum * (1.f / 256.f);
      float s2 = 0.f;
      #pragma unroll
      for (int k = 0; k < 4; k++){ float d = v[k] - mu; s2 += d * d; }
      s2 = rsum64(s2);
      float rs = rsqrtf(s2 * (1.f / 256.f) + 1e-5f);
      #pragma unroll
      for (int k = 0; k < 4; k++){
        int c = cc + (k << 6);
        v[k] = (v[k] - mu) * rs * g2[c] + bn2[c];
      }
      if (lw == 3){
        float sum2 = 0.f;
        #pragma unroll
        for (int k = 0; k < 4; k++) sum2 += v[k];
        sum2 = rsum64(sum2);
        float mu2 = sum2 * (1.f / 256.f);
        float s22 = 0.f;
        #pragma unroll
        for (int k = 0; k < 4; k++){ float d = v[k] - mu2; s22 += d * d; }
        s22 = rsum64(s22);
        float rs2 = rsqrtf(s22 * (1.f / 256.f) + 1e-5f);
        int t_out = (l >> 2) + 1;
        size_t mbase = (size_t)(t_out * 8 + wg) * 8;
        #pragma unroll
        for (int k = 0; k < 4; k++){
          int c = cc + (k << 6);
          float o2 = (v[k] - mu2) * rs2 * dng[c] + dnb[c];
          res[row][c] = o2;
          unsigned short bv = f2bf(o2);
          A0[afidx(row, c)] = bv;
          predsf[((mbase + (c >> 5)) << 9) + ((row + (((c >> 3) & 3) << 4)) << 3) + (c & 7)] = bv;
        }
      } else {
        #pragma unroll
        for (int k = 0; k < 4; k++){
          int c = cc + (k << 6);
          res[row][c] = v[k];
          A0[afidx(row, c)] = f2bf(v[k]);
        }
      }
    }
    __syncthreads();
  }
}

// ---------------- decoder: out[b,t,:] = preds[t,b,:] @ dec_W + dec_b ----------------
__global__ void dec_gemm(const unsigned short* __restrict__ predsf, const unsigned short* __restrict__ decWf,
                         const float* __restrict__ dec_b, float* __restrict__ out)
{
  __shared__ float cs[128][68];
  int bid = blockIdx.x;
  int nb = bid & 255, mb = bid >> 8;
  int tid = threadIdx.x, lane = tid & 63, w = tid >> 6;
  int g = lane >> 4, c0 = lane & 15;
  f32x4 zero = {0.f, 0.f, 0.f, 0.f};
  f32x4 acc[2][4] = {{zero, zero, zero, zero}, {zero, zero, zero, zero}};
  #pragma unroll
  for (int kt = 0; kt < 8; kt++){
    bf16x8 a0 = *(const bf16x8*)(predsf + (((size_t)(mb * 8 + 2 * w    ) * 8 + kt) << 9) + lane * 8);
    bf16x8 a1 = *(const bf16x8*)(predsf + (((size_t)(mb * 8 + 2 * w + 1) * 8 + kt) << 9) + lane * 8);
    #pragma unroll
    for (int i = 0; i < 4; i++){
      bf16x8 b = *(const bf16x8*)(decWf + (((size_t)(nb * 4 + i) * 8 + kt) << 9) + lane * 8);
      acc[0][i] = mfma16(a0, b, acc[0][i]);
      acc[1][i] = mfma16(a1, b, acc[1][i]);
    }
  }
  #pragma unroll
  for (int mi = 0; mi < 2; mi++)
    #pragma unroll
    for (int i = 0; i < 4; i++)
      #pragma unroll
      for (int reg = 0; reg < 4; reg++)
        cs[(2 * w + mi) * 16 + g * 4 + reg][i * 16 + c0] = acc[mi][i][reg];
  __syncthreads();
  int row = tid >> 1, seg = tid & 1;   // row == batch index b; t == mb
  #pragma unroll
  for (int q = 0; q < 8; q++){
    int c = seg * 32 + q * 4;
    float4 vv = *(float4*)&cs[row][c];
    float4 db = *(const float4*)(dec_b + nb * 64 + c);
    vv.x += db.x; vv.y += db.y; vv.z += db.z; vv.w += db.w;
    *(float4*)(out + ((size_t)row * 30 + mb) * IMGSZ + nb * 64 + c) = vv;
  }
}

extern "C" void kernel_launch(void* const* d_in, const int* in_sizes, int n_in,
                              void* d_out, int out_size, void* d_ws, size_t ws_size,
                              hipStream_t stream)
{
  (void)in_sizes; (void)n_in; (void)out_size; (void)ws_size;
  const float* x      = (const float*)d_in[0];
  const float* enc_W  = (const float*)d_in[1];
  const float* enc_b  = (const float*)d_in[2];
  const float* encn_g = (const float*)d_in[3];
  const float* encn_b = (const float*)d_in[4];
  const float* dec_W  = (const float*)d_in[5];
  const float* dec_b  = (const float*)d_in[6];
  const float* decn_g = (const float*)d_in[7];
  const float* decn_b = (const float*)d_in[8];
  const float* Wqkv   = (const float*)d_in[9];
  const float* bqkv   = (const float*)d_in[10];
  const float* Wo     = (const float*)d_in[11];
  const float* bo     = (const float*)d_in[12];
  const float* W1     = (const float*)d_in[13];
  const float* b1     = (const float*)d_in[14];
  const float* W2     = (const float*)d_in[15];
  const float* b2     = (const float*)d_in[16];
  const float* ln1_g  = (const float*)d_in[17];
  const float* ln1_b  = (const float*)d_in[18];
  const float* ln2_g  = (const float*)d_in[19];
  const float* ln2_b  = (const float*)d_in[20];

  char* ws = (char*)d_ws;
  // ws layout (all offsets 512B-aligned), total ~26.5 MB
  unsigned int* bar      = (unsigned int*)(ws);              // 512 B
  float* s0              = (float*)(ws + 512);               // 128*256*4      = 131072
  float* part            = (float*)(ws + 131584);            // 32*128*256*4   = 4194304
  unsigned short* encWf  = (unsigned short*)(ws + 4325888);  // 8192*1024      = 8388608
  unsigned short* decWf  = (unsigned short*)(ws + 12714496); // 8192*1024      = 8388608
  unsigned short* scanWf = (unsigned short*)(ws + 21103104); // 3072*1024      = 3145728
  unsigned short* predsf = (unsigned short*)(ws + 24248832); // 240*8*1024     = 1966080
  unsigned short* kvf    = (unsigned short*)(ws + 26214912); // 2*128*1024     = 262144

  hipMemsetAsync(bar, 0, 512, stream);
  pack_weights<<<4864, 256, 0, stream>>>(enc_W, dec_W, Wqkv, Wo, W1, W2, encWf, decWf, scanWf);
  enc_gemm<<<256, 256, 0, stream>>>(x, encWf, part);
  enc_ln<<<8, 256, 0, stream>>>(part, enc_b, encn_g, encn_b, s0, predsf);
  scan_kernel<<<NWG, 1024, 0, stream>>>(s0, scanWf, bqkv, bo, b1, b2,
                                        ln1_g, ln1_b, ln2_g, ln2_b,
                                        decn_g, decn_b, kvf, predsf, bar);
  dec_gemm<<<30 * 256, 256, 0, stream>>>(predsf, decWf, dec_b, (float*)d_out);
}